// Round 7
// baseline (403.343 us; speedup 1.0000x reference)
//
#include <hip/hip_runtime.h>
#include <math.h>

#ifndef M_PI
#define M_PI 3.14159265358979323846
#endif

#define T_LEN 4096
#define M_LEN 2048   // T/2, complex FFT length
#define NFREQ 2049   // T/2 + 1
#define KM 8         // modes
#define LI 8         // iterations
#define CD 16        // channels

// ---------------- complex helpers ----------------
__device__ __forceinline__ float2 cadd(float2 a, float2 b){ return make_float2(a.x+b.x, a.y+b.y); }
__device__ __forceinline__ float2 csub(float2 a, float2 b){ return make_float2(a.x-b.x, a.y-b.y); }
__device__ __forceinline__ float2 cmul(float2 a, float2 b){ return make_float2(a.x*b.x - a.y*b.y, a.x*b.y + a.y*b.x); }
#define RC 0.70710678118654752440f

// SGN = +1: inverse (e^{+i...}); SGN = -1: forward (e^{-i...}).
template<int SGN>
__device__ __forceinline__ float2 muli_s(float2 a){   // * (SGN * i)
    return (SGN > 0) ? make_float2(-a.y, a.x) : make_float2(a.y, -a.x);
}
template<int SGN>
__device__ __forceinline__ float2 w81_s(float2 a){    // * (c + SGN*ic)
    return (SGN > 0) ? make_float2(RC*(a.x-a.y), RC*(a.x+a.y))
                     : make_float2(RC*(a.x+a.y), RC*(a.y-a.x));
}
template<int SGN>
__device__ __forceinline__ float2 w83_s(float2 a){    // * (-c + SGN*ic)
    return (SGN > 0) ? make_float2(-RC*(a.x+a.y), RC*(a.x-a.y))
                     : make_float2(RC*(a.y-a.x), -RC*(a.x+a.y));
}

// LDS XOR swizzle on float2 index (bijective; bank-conflict fix validated:
// SQ_LDS_BANK_CONFLICT 4.19M -> 1.56M).
#define SWZ(i) ((i) ^ (((i) >> 4) & 15))

// 8-point DFT, sign-templated, natural order in/out.
template<int SGN>
__device__ __forceinline__ void dft8_s(const float2 a[8], float2 x[8]) {
    float2 s0=cadd(a[0],a[4]), s1=cadd(a[1],a[5]), s2=cadd(a[2],a[6]), s3=cadd(a[3],a[7]);
    float2 d0=csub(a[0],a[4]), d1=csub(a[1],a[5]), d2=csub(a[2],a[6]), d3=csub(a[3],a[7]);
    d1 = w81_s<SGN>(d1); d2 = muli_s<SGN>(d2); d3 = w83_s<SGN>(d3);
    float2 e0=cadd(s0,s2), e2=csub(s0,s2), e1=cadd(s1,s3), e3=muli_s<SGN>(csub(s1,s3));
    float2 f0=cadd(d0,d2), f2=csub(d0,d2), f1=cadd(d1,d3), f3=muli_s<SGN>(csub(d1,d3));
    x[0]=cadd(e0,e1); x[4]=csub(e0,e1); x[2]=cadd(e2,e3); x[6]=csub(e2,e3);
    x[1]=cadd(f0,f1); x[5]=csub(f0,f1); x[3]=cadd(f2,f3); x[7]=csub(f2,f3);
}

// One Stockham radix-8 stage, in-place via regs + 2 barriers. 256 threads/2048 pts.
// Reads S[i + k*256], writes S[(i%m) + (8*(i/m)+k)*m], twiddle W_2048^{SGN*k*j*m}.
// Twiddle powers computed incrementally and applied immediately (short live-range:
// only {w1, w} live, vs w1..w7 = 14 regs in the r4-r6 version).
template<int MSTAGE, int SGN>
__device__ __forceinline__ void r8_stage(float2* S, int lt) {
    float2 a[8];
    #pragma unroll
    for (int k = 0; k < 8; ++k) a[k] = S[SWZ(lt + 256*k)];
    __syncthreads();
    float2 x[8];
    dft8_s<SGN>(a, x);
    const int j = lt / MSTAGE;
    const int r = lt % MSTAGE;
    float th = (float)SGN * ((float)M_PI / 1024.0f) * (float)(j * MSTAGE);
    float swv, cwv; __sincosf(th, &swv, &cwv);
    const float2 w1 = make_float2(cwv, swv);
    float2 w = w1;
    x[1] = cmul(x[1], w);
    #pragma unroll
    for (int k = 2; k < 8; ++k) {
        w = cmul(w, w1);
        x[k] = cmul(x[k], w);
    }
    const int base = r + 8*MSTAGE*j;
    #pragma unroll
    for (int k = 0; k < 8; ++k) S[SWZ(base + MSTAGE*k)] = x[k];
    __syncthreads();
}

// Final radix-4 stage (m=512, j=0 -> twiddle-free), 2 butterflies/thread, in place.
template<int SGN>
__device__ __forceinline__ void r4_stage_pair(float2* S, int lt) {
    float2 b[2][4];
    #pragma unroll
    for (int h = 0; h < 2; ++h) {
        int i2 = lt + 256*h;
        #pragma unroll
        for (int k = 0; k < 4; ++k) b[h][k] = S[SWZ(i2 + 512*k)];
    }
    __syncthreads();
    #pragma unroll
    for (int h = 0; h < 2; ++h) {
        int i2 = lt + 256*h;
        float2 s02=cadd(b[h][0],b[h][2]), d02=csub(b[h][0],b[h][2]);
        float2 s13=cadd(b[h][1],b[h][3]), d13=muli_s<SGN>(csub(b[h][1],b[h][3]));
        S[SWZ(i2 +    0)] = cadd(s02,s13);
        S[SWZ(i2 +  512)] = cadd(d02,d13);
        S[SWZ(i2 + 1024)] = csub(s02,s13);
        S[SWZ(i2 + 1536)] = csub(d02,d13);
    }
    __syncthreads();
}

// K1: 512 threads, 2 rows (b,c) per block. Forward radix-8 rfft + Jacobi.
// (UNCHANGED this round; becomes top dispatch next round.)
__global__ void __launch_bounds__(512)
k_fwd_iter(const float* __restrict__ x,
           const float* __restrict__ log_alpha,
           const float* __restrict__ raw_tau,
           const float* __restrict__ raw_omega,
           float2* __restrict__ u_ws)
{
    __shared__ float2 S[2][M_LEN];    // 32 KB
    __shared__ float s_2a[LI * KM];
    __shared__ float s_tau[LI];
    __shared__ float s_om[KM];

    const int tid = threadIdx.x;
    const int g   = tid >> 8;         // row slot 0..1
    const int lt  = tid & 255;
    const int row = blockIdx.x * 2 + g;   // b*16 + c
    const int b = row >> 4;
    const int c = row & 15;

    if (tid < LI * KM) s_2a[tid] = 2.0f * __expf(log_alpha[tid]);
    if (tid < LI)      s_tau[tid] = log1pf(__expf(raw_tau[tid]));
    if (tid < KM)      s_om[tid]  = 0.5f / (1.0f + __expf(-raw_omega[tid]));

    // pack z[n] = x[2n] + i*x[2n+1]
    const float* xr = x + (size_t)b * T_LEN * CD + c;
    #pragma unroll
    for (int q = 0; q < 8; ++q) {
        int n = lt + 256 * q;
        float e = xr[(size_t)(2 * n) * CD];
        float o = xr[(size_t)(2 * n + 1) * CD];
        S[g][SWZ(n)] = make_float2(e, o);
    }
    __syncthreads();

    r8_stage<1,  -1>(S[g], lt);
    r8_stage<8,  -1>(S[g], lt);
    r8_stage<64, -1>(S[g], lt);
    r4_stage_pair<-1>(S[g], lt);      // S[g] now holds forward FFT Z (swizzled)

    const size_t sb = (size_t)(b * (KM * CD) + c);

    for (int f = lt; f < NFREQ; f += 256) {
        float2 Zk = S[g][SWZ(f & (M_LEN - 1))];
        float2 Zm = S[g][SWZ((M_LEN - f) & (M_LEN - 1))];
        float2 E = make_float2(0.5f * (Zk.x + Zm.x), 0.5f * (Zk.y - Zm.y));
        float2 D = make_float2(0.5f * (Zk.x - Zm.x), 0.5f * (Zk.y + Zm.y));
        float2 O = make_float2(D.y, -D.x);
        float ang = -2.0f * (float)M_PI * (float)f / (float)T_LEN;
        float sw, cw;
        __sincosf(ang, &sw, &cw);
        float fhx = E.x + cw * O.x - sw * O.y;
        float fhy = E.y + cw * O.y + sw * O.x;

        float freq = (float)f * (0.5f / (float)M_LEN);
        float dd[KM];
        #pragma unroll
        for (int k = 0; k < KM; ++k) {
            float d = freq - s_om[k];
            dd[k] = d * d;
        }

        float2 u[KM];
        #pragma unroll
        for (int k = 0; k < KM; ++k) u[k] = make_float2(0.f, 0.f);
        float lamx = 0.f, lamy = 0.f;

        #pragma unroll
        for (int l = 0; l < LI; ++l) {
            float usx = 0.f, usy = 0.f;
            #pragma unroll
            for (int k = 0; k < KM; ++k) { usx += u[k].x; usy += u[k].y; }
            float bx = fhx - usx + 0.5f * lamx;
            float by = fhy - usy + 0.5f * lamy;
            float sx = 0.f, sy = 0.f;
            #pragma unroll
            for (int k = 0; k < KM; ++k) {
                float den = fmaf(s_2a[l * KM + k], dd[k], 1.0f);
                float r = __builtin_amdgcn_rcpf(den);
                float ux = (bx + u[k].x) * r;
                float uy = (by + u[k].y) * r;
                u[k].x = ux; u[k].y = uy;
                sx += ux; sy += uy;
            }
            lamx += s_tau[l] * (fhx - sx);
            lamy += s_tau[l] * (fhy - sy);
        }

        #pragma unroll
        for (int k = 0; k < KM; ++k) {
            u_ws[(sb + (size_t)k * CD) * NFREQ + f] = u[k];
        }
    }
}

// ---- one k_inv pass; CP template const; outputs go to 4 NAMED float4 refs.
// r6 lesson: even a fully statically-indexed local ARRAY threaded by reference
// through inlined calls across 40 barriers gets alloca'd -> scratch (FETCH/WRITE
// +134 MB each, VGPR pinned at 64). Named scalars cannot be alloca'd.
template<int CP>
__device__ __forceinline__ void inv_pass(const float2* __restrict__ u_ws,
                                         float2 S[4][M_LEN],
                                         int tid, int g, int lt, int bk,
                                         float4& o0, float4& o1,
                                         float4& o2, float4& o3)
{
    const float sc = 1.0f / (float)M_LEN;
    const float2* sp = u_ws + (size_t)(bk * CD + 4 * CP + g) * NFREQ;

    // fill: coalesced 1x read of the spectrum into LDS
    #pragma unroll
    for (int q = 0; q < 8; ++q) {
        int n = lt + 256 * q;
        S[g][SWZ(n)] = sp[n];
    }
    __syncthreads();

    // in-place irfft repack: thread lt owns slot pairs (j, 2048-j), no hazard
    #pragma unroll
    for (int q = 0; q < 4; ++q) {
        int j = lt + 256 * q;
        float2 Xj = S[g][SWZ(j)];
        float2 Xm = (j > 0) ? S[g][SWZ(M_LEN - j)] : sp[M_LEN];  // Nyquist from global
        float Ex = 0.5f * (Xj.x + Xm.x), Ey = 0.5f * (Xj.y - Xm.y);
        float Dx = 0.5f * (Xj.x - Xm.x), Dy = 0.5f * (Xj.y + Xm.y);
        float ang = (2.0f * (float)M_PI / (float)T_LEN) * (float)j;
        float swv, cwv;
        __sincosf(ang, &swv, &cwv);
        float Ox = cwv * Dx - swv * Dy;
        float Oy = cwv * Dy + swv * Dx;
        if (j > 0) {
            S[g][SWZ(j)]         = make_float2((Ex - Oy) * sc, (Ey + Ox) * sc);
            S[g][SWZ(M_LEN - j)] = make_float2((Ex + Oy) * sc, (Ox - Ey) * sc);
        } else {
            float2 Xq = S[g][SWZ(1024)];        // self-paired bin
            S[g][SWZ(0)]    = make_float2((Ex - Oy) * sc, (Ey + Ox) * sc);
            S[g][SWZ(1024)] = make_float2(Xq.x * sc, -Xq.y * sc);
        }
    }
    __syncthreads();

    // 2048 = 8 * 8 * 8 * 4, inverse sign
    r8_stage<1,  1>(S[g], lt);
    r8_stage<8,  1>(S[g], lt);
    r8_stage<64, 1>(S[g], lt);
    r4_stage_pair<1>(S[g], lt);

    // readout: channels 4*CP .. 4*CP+3, t = 4*tid + {0,1,2,3}
    {
        float2 z0 = S[0][SWZ(2 * tid)], z1 = S[0][SWZ(2 * tid + 1)];
        o0 = make_float4(z0.x, z0.y, z1.x, z1.y);
    }
    {
        float2 z0 = S[1][SWZ(2 * tid)], z1 = S[1][SWZ(2 * tid + 1)];
        o1 = make_float4(z0.x, z0.y, z1.x, z1.y);
    }
    {
        float2 z0 = S[2][SWZ(2 * tid)], z1 = S[2][SWZ(2 * tid + 1)];
        o2 = make_float4(z0.x, z0.y, z1.x, z1.y);
    }
    {
        float2 z0 = S[3][SWZ(2 * tid)], z1 = S[3][SWZ(2 * tid + 1)];
        o3 = make_float4(z0.x, z0.y, z1.x, z1.y);
    }
    __syncthreads();              // S free for next pass's fill
}

__device__ __forceinline__ float f4c(float4 v, int r) {
    return r == 0 ? v.x : r == 1 ? v.y : r == 2 ? v.z : v.w;   // r is unroll-const
}

// K2: one block per (b,k). 16 inverse rffts as 4 template-expanded passes x 4
// channels. Cross-pass state = 16 NAMED float4 scalars (register/AGPR-resident
// by construction). Final store: contiguous 256 B per thread (full lines; r5's
// per-pass 16B-stride stores caused RMW amplification).
// __launch_bounds__(1024, 4): 1 block/CU of 16 waves -> 128-reg unified budget.
__global__ void __launch_bounds__(1024, 4)
k_inv(const float2* __restrict__ u_ws, float* __restrict__ out)
{
    __shared__ float2 S[4][M_LEN];    // 64 KB, swizzled indexing

    const int tid = threadIdx.x;
    const int g   = tid >> 8;         // channel slot 0..3
    const int lt  = tid & 255;
    const int bk  = blockIdx.x;       // b*8 + k

    float4 v0, v1, v2, v3, v4, v5, v6, v7, v8, v9, v10, v11, v12, v13, v14, v15;

    inv_pass<0>(u_ws, S, tid, g, lt, bk, v0,  v1,  v2,  v3);
    inv_pass<1>(u_ws, S, tid, g, lt, bk, v4,  v5,  v6,  v7);
    inv_pass<2>(u_ws, S, tid, g, lt, bk, v8,  v9,  v10, v11);
    inv_pass<3>(u_ws, S, tid, g, lt, bk, v12, v13, v14, v15);

    // Assemble (no barriers crossed from here on -> trivially SROA'd).
    float4 val[CD] = {v0, v1, v2,  v3,  v4,  v5,  v6,  v7,
                      v8, v9, v10, v11, v12, v13, v14, v15};

    // Each thread owns out[b, k, 4*tid .. 4*tid+3, 0..15]: contiguous 256 B.
    float4* op = (float4*)(out + ((size_t)bk * T_LEN + (size_t)(4 * tid)) * CD);
    #pragma unroll
    for (int r = 0; r < 4; ++r) {
        #pragma unroll
        for (int g2 = 0; g2 < 4; ++g2) {
            op[r * 4 + g2] = make_float4(f4c(val[4 * g2 + 0], r),
                                         f4c(val[4 * g2 + 1], r),
                                         f4c(val[4 * g2 + 2], r),
                                         f4c(val[4 * g2 + 3], r));
        }
    }
}

extern "C" void kernel_launch(void* const* d_in, const int* in_sizes, int n_in,
                              void* d_out, int out_size, void* d_ws, size_t ws_size,
                              hipStream_t stream) {
    const float* x         = (const float*)d_in[0];
    const float* log_alpha = (const float*)d_in[1];
    const float* raw_tau   = (const float*)d_in[2];
    const float* raw_omega = (const float*)d_in[3];
    float* out = (float*)d_out;
    float2* u_ws = (float2*)d_ws;   // needs 8192 * 2049 * 8 B = 134.3 MB

    k_fwd_iter<<<dim3(64 * CD / 2), dim3(512), 0, stream>>>(x, log_alpha, raw_tau,
                                                            raw_omega, u_ws);
    k_inv<<<dim3(64 * KM), dim3(1024), 0, stream>>>(u_ws, out);
}

// Round 9
// 393.915 us; speedup vs baseline: 1.0239x; 1.0239x over previous
//
#include <hip/hip_runtime.h>
#include <math.h>

#ifndef M_PI
#define M_PI 3.14159265358979323846
#endif

#define T_LEN 4096
#define M_LEN 2048   // T/2, complex FFT length
#define NFREQ 2049   // T/2 + 1
#define KM 8         // modes
#define LI 8         // iterations
#define CD 16        // channels

// ---------------- complex helpers ----------------
__device__ __forceinline__ float2 cadd(float2 a, float2 b){ return make_float2(a.x+b.x, a.y+b.y); }
__device__ __forceinline__ float2 csub(float2 a, float2 b){ return make_float2(a.x-b.x, a.y-b.y); }
__device__ __forceinline__ float2 cmul(float2 a, float2 b){ return make_float2(a.x*b.x - a.y*b.y, a.x*b.y + a.y*b.x); }
#define RC 0.70710678118654752440f

// SGN = +1: inverse (e^{+i...}); SGN = -1: forward (e^{-i...}).
template<int SGN>
__device__ __forceinline__ float2 muli_s(float2 a){   // * (SGN * i)
    return (SGN > 0) ? make_float2(-a.y, a.x) : make_float2(a.y, -a.x);
}
template<int SGN>
__device__ __forceinline__ float2 w81_s(float2 a){    // * (c + SGN*ic)
    return (SGN > 0) ? make_float2(RC*(a.x-a.y), RC*(a.x+a.y))
                     : make_float2(RC*(a.x+a.y), RC*(a.y-a.x));
}
template<int SGN>
__device__ __forceinline__ float2 w83_s(float2 a){    // * (-c + SGN*ic)
    return (SGN > 0) ? make_float2(-RC*(a.x+a.y), RC*(a.x-a.y))
                     : make_float2(RC*(a.y-a.x), -RC*(a.x+a.y));
}

// LDS XOR swizzle on float2 index (bijective; used by the radix-8 k_fwd engine).
#define SWZ(i) ((i) ^ (((i) >> 4) & 15))

// 8-point DFT, sign-templated, natural order in/out.
template<int SGN>
__device__ __forceinline__ void dft8_s(const float2 a[8], float2 x[8]) {
    float2 s0=cadd(a[0],a[4]), s1=cadd(a[1],a[5]), s2=cadd(a[2],a[6]), s3=cadd(a[3],a[7]);
    float2 d0=csub(a[0],a[4]), d1=csub(a[1],a[5]), d2=csub(a[2],a[6]), d3=csub(a[3],a[7]);
    d1 = w81_s<SGN>(d1); d2 = muli_s<SGN>(d2); d3 = w83_s<SGN>(d3);
    float2 e0=cadd(s0,s2), e2=csub(s0,s2), e1=cadd(s1,s3), e3=muli_s<SGN>(csub(s1,s3));
    float2 f0=cadd(d0,d2), f2=csub(d0,d2), f1=cadd(d1,d3), f3=muli_s<SGN>(csub(d1,d3));
    x[0]=cadd(e0,e1); x[4]=csub(e0,e1); x[2]=cadd(e2,e3); x[6]=csub(e2,e3);
    x[1]=cadd(f0,f1); x[5]=csub(f0,f1); x[3]=cadd(f2,f3); x[7]=csub(f2,f3);
}

// One Stockham radix-8 stage, in-place via regs + 2 barriers. 256 threads/2048 pts.
template<int MSTAGE, int SGN>
__device__ __forceinline__ void r8_stage(float2* S, int lt) {
    float2 a[8];
    #pragma unroll
    for (int k = 0; k < 8; ++k) a[k] = S[SWZ(lt + 256*k)];
    __syncthreads();
    float2 x[8];
    dft8_s<SGN>(a, x);
    const int j = lt / MSTAGE;
    const int r = lt % MSTAGE;
    float th = (float)SGN * ((float)M_PI / 1024.0f) * (float)(j * MSTAGE);
    float swv, cwv; __sincosf(th, &swv, &cwv);
    const float2 w1 = make_float2(cwv, swv);
    float2 w = w1;
    x[1] = cmul(x[1], w);
    #pragma unroll
    for (int k = 2; k < 8; ++k) {
        w = cmul(w, w1);
        x[k] = cmul(x[k], w);
    }
    const int base = r + 8*MSTAGE*j;
    #pragma unroll
    for (int k = 0; k < 8; ++k) S[SWZ(base + MSTAGE*k)] = x[k];
    __syncthreads();
}

// Final radix-4 stage (m=512, j=0 -> twiddle-free), 2 butterflies/thread, in place.
template<int SGN>
__device__ __forceinline__ void r4_stage_pair(float2* S, int lt) {
    float2 b[2][4];
    #pragma unroll
    for (int h = 0; h < 2; ++h) {
        int i2 = lt + 256*h;
        #pragma unroll
        for (int k = 0; k < 4; ++k) b[h][k] = S[SWZ(i2 + 512*k)];
    }
    __syncthreads();
    #pragma unroll
    for (int h = 0; h < 2; ++h) {
        int i2 = lt + 256*h;
        float2 s02=cadd(b[h][0],b[h][2]), d02=csub(b[h][0],b[h][2]);
        float2 s13=cadd(b[h][1],b[h][3]), d13=muli_s<SGN>(csub(b[h][1],b[h][3]));
        S[SWZ(i2 +    0)] = cadd(s02,s13);
        S[SWZ(i2 +  512)] = cadd(d02,d13);
        S[SWZ(i2 + 1024)] = csub(s02,s13);
        S[SWZ(i2 + 1536)] = csub(d02,d13);
    }
    __syncthreads();
}

// Stockham radix-2 DIF, N=2048, ping-pong (r0's proven k_inv engine).
template <int NT>
__device__ __forceinline__ float2* fft2048(float2* a, float2* b, int tid, float sign) {
    float2* src = a;
    float2* dst = b;
    int l = 1024;
    #pragma unroll 1
    for (int s = 0; s < 11; ++s) {
        float piol = sign * (float)M_PI / (float)l;
        #pragma unroll
        for (int ii = 0; ii < 1024 / NT; ++ii) {
            int i = tid + ii * NT;
            int j = i >> s;
            float2 A = src[i];
            float2 B = src[i + 1024];
            float ang = piol * (float)j;
            float sw, cw;
            __sincosf(ang, &sw, &cw);
            float2 sum = make_float2(A.x + B.x, A.y + B.y);
            float2 dif = make_float2(A.x - B.x, A.y - B.y);
            float2 tw = make_float2(dif.x * cw - dif.y * sw, dif.x * sw + dif.y * cw);
            int p = i + (j << s);
            dst[p] = sum;
            dst[p + (1 << s)] = tw;
        }
        __syncthreads();
        float2* t = src; src = dst; dst = t;
        l >>= 1;
    }
    return src;
}

// K1: 512 threads, 2 rows (b,c) per block. Forward radix-8 rfft (validated
// r5-r8) + Jacobi with reduced algebra:
//  - carry s = SUM(u) across layers (old code re-summed 8 complex u every layer
//    even though the previous layer's accumulation already produced it)
//  - track h = 0.5*lambda with pre-halved tau (kills the 0.5* muls)
//  - layer 0 special-cased (u=0 -> u[k] = b*r[k])
// All algebraically exact vs the reference recurrence.
__global__ void __launch_bounds__(512)
k_fwd_iter(const float* __restrict__ x,
           const float* __restrict__ log_alpha,
           const float* __restrict__ raw_tau,
           const float* __restrict__ raw_omega,
           float2* __restrict__ u_ws)
{
    __shared__ float2 S[2][M_LEN];    // 32 KB
    __shared__ float s_2a[LI * KM];
    __shared__ float s_tau2[LI];      // 0.5 * softplus(raw_tau)
    __shared__ float s_om[KM];

    const int tid = threadIdx.x;
    const int g   = tid >> 8;         // row slot 0..1
    const int lt  = tid & 255;
    const int row = blockIdx.x * 2 + g;   // b*16 + c
    const int b = row >> 4;
    const int c = row & 15;

    if (tid < LI * KM) s_2a[tid]  = 2.0f * __expf(log_alpha[tid]);
    if (tid < LI)      s_tau2[tid] = 0.5f * log1pf(__expf(raw_tau[tid]));
    if (tid < KM)      s_om[tid]  = 0.5f / (1.0f + __expf(-raw_omega[tid]));

    // pack z[n] = x[2n] + i*x[2n+1]
    const float* xr = x + (size_t)b * T_LEN * CD + c;
    #pragma unroll
    for (int q = 0; q < 8; ++q) {
        int n = lt + 256 * q;
        float e = xr[(size_t)(2 * n) * CD];
        float o = xr[(size_t)(2 * n + 1) * CD];
        S[g][SWZ(n)] = make_float2(e, o);
    }
    __syncthreads();

    r8_stage<1,  -1>(S[g], lt);
    r8_stage<8,  -1>(S[g], lt);
    r8_stage<64, -1>(S[g], lt);
    r4_stage_pair<-1>(S[g], lt);      // S[g] now holds forward FFT Z (swizzled)

    const size_t sb = (size_t)(b * (KM * CD) + c);

    for (int f = lt; f < NFREQ; f += 256) {
        float2 Zk = S[g][SWZ(f & (M_LEN - 1))];
        float2 Zm = S[g][SWZ((M_LEN - f) & (M_LEN - 1))];
        float2 E = make_float2(0.5f * (Zk.x + Zm.x), 0.5f * (Zk.y - Zm.y));
        float2 D = make_float2(0.5f * (Zk.x - Zm.x), 0.5f * (Zk.y + Zm.y));
        float2 O = make_float2(D.y, -D.x);
        float ang = -2.0f * (float)M_PI * (float)f / (float)T_LEN;
        float sw, cw;
        __sincosf(ang, &sw, &cw);
        float fhx = E.x + cw * O.x - sw * O.y;
        float fhy = E.y + cw * O.y + sw * O.x;

        float freq = (float)f * (0.5f / (float)M_LEN);
        float dd[KM];
        #pragma unroll
        for (int k = 0; k < KM; ++k) {
            float d = freq - s_om[k];
            dd[k] = d * d;
        }

        float2 u[KM];
        float sx, sy;                 // carried SUM(u)
        float hx = 0.f, hy = 0.f;     // 0.5 * lambda

        // ---- layer 0: u=0, lambda=0 -> b = fh, u[k] = b * r[k] ----
        {
            float nsx = 0.f, nsy = 0.f;
            #pragma unroll
            for (int k = 0; k < KM; ++k) {
                float den = fmaf(s_2a[k], dd[k], 1.0f);
                float r = __builtin_amdgcn_rcpf(den);
                float ux = fhx * r;
                float uy = fhy * r;
                u[k].x = ux; u[k].y = uy;
                nsx += ux; nsy += uy;
            }
            hx = s_tau2[0] * (fhx - nsx);
            hy = s_tau2[0] * (fhy - nsy);
            sx = nsx; sy = nsy;
        }

        // ---- layers 1..7 ----
        #pragma unroll
        for (int l = 1; l < LI; ++l) {
            float bx = fhx - sx + hx;
            float by = fhy - sy + hy;
            float nsx = 0.f, nsy = 0.f;
            #pragma unroll
            for (int k = 0; k < KM; ++k) {
                float den = fmaf(s_2a[l * KM + k], dd[k], 1.0f);
                float r = __builtin_amdgcn_rcpf(den);
                float ux = (bx + u[k].x) * r;
                float uy = (by + u[k].y) * r;
                u[k].x = ux; u[k].y = uy;
                nsx += ux; nsy += uy;
            }
            hx += s_tau2[l] * (fhx - nsx);
            hy += s_tau2[l] * (fhy - nsy);
            sx = nsx; sy = nsy;
        }

        #pragma unroll
        for (int k = 0; k < KM; ++k) {
            u_ws[(sb + (size_t)k * CD) * NFREQ + f] = u[k];
        }
    }
}

// K2: r0's proven kernel, restored byte-for-byte (188 us, VGPR 44, AGPR-resident
// val[], FETCH 66 MB / WRITE 143 MB — the only k_inv that ever ran clean).
// One block per (b,k): 16 sequential inverse rffts, registers staged for a
// contiguous 256 B store per thread. Radix-8 / cross-pass-state variants
// (r4-r8) all lost to the register allocator; do not revisit without disasm.
__global__ void __launch_bounds__(1024)
k_inv(const float2* __restrict__ u_ws, float* __restrict__ out)
{
    __shared__ float2 bufA[NFREQ];
    __shared__ float2 bufB[M_LEN];
    const int tid = threadIdx.x;
    const int bk = blockIdx.x;        // b*8 + k

    float val[CD][4];                 // [c][t offset], 64 VGPRs

    #pragma unroll
    for (int c = 0; c < CD; ++c) {
        const float2* sp = u_ws + (size_t)(bk * CD + c) * NFREQ;
        bufA[tid] = sp[tid];
        bufA[tid + 1024] = sp[tid + 1024];
        if (tid == 0) bufA[2048] = sp[2048];
        __syncthreads();

        // irfft repack: Z[j] = (E[j] + i*O[j]) / M
        #pragma unroll
        for (int jj = 0; jj < 2; ++jj) {
            int j = tid + jj * 1024;
            float2 Xj = bufA[j];
            float2 Xm = bufA[M_LEN - j];          // j=0 -> Nyquist (2048)
            float2 E = make_float2(0.5f * (Xj.x + Xm.x), 0.5f * (Xj.y - Xm.y));
            float2 D = make_float2(0.5f * (Xj.x - Xm.x), 0.5f * (Xj.y + Xm.y));
            float ang = 2.0f * (float)M_PI * (float)j / (float)T_LEN;
            float sw, cw;
            __sincosf(ang, &sw, &cw);
            float2 O = make_float2(cw * D.x - sw * D.y, cw * D.y + sw * D.x);
            const float sc = 1.0f / (float)M_LEN;
            bufB[j] = make_float2((E.x - O.y) * sc, (E.y + O.x) * sc);
        }
        __syncthreads();

        float2* res = fft2048<1024>(bufB, bufA, tid, 1.0f);  // ends in bufA
        float2 z0 = res[2 * tid];
        float2 z1 = res[2 * tid + 1];
        val[c][0] = z0.x;   // t = 4*tid + 0 (even -> Re)
        val[c][1] = z0.y;   // t = 4*tid + 1 (odd  -> Im)
        val[c][2] = z1.x;
        val[c][3] = z1.y;
        __syncthreads();    // before next c overwrites buffers
    }

    // Each thread owns out[b, k, 4*tid .. 4*tid+3, 0..15]: contiguous 64 floats.
    float4* op = (float4*)(out + ((size_t)bk * T_LEN + (size_t)(4 * tid)) * CD);
    #pragma unroll
    for (int r = 0; r < 4; ++r) {
        #pragma unroll
        for (int g = 0; g < 4; ++g) {
            op[r * 4 + g] = make_float4(val[4 * g + 0][r], val[4 * g + 1][r],
                                        val[4 * g + 2][r], val[4 * g + 3][r]);
        }
    }
}

extern "C" void kernel_launch(void* const* d_in, const int* in_sizes, int n_in,
                              void* d_out, int out_size, void* d_ws, size_t ws_size,
                              hipStream_t stream) {
    const float* x         = (const float*)d_in[0];
    const float* log_alpha = (const float*)d_in[1];
    const float* raw_tau   = (const float*)d_in[2];
    const float* raw_omega = (const float*)d_in[3];
    float* out = (float*)d_out;
    float2* u_ws = (float2*)d_ws;   // needs 8192 * 2049 * 8 B = 134.3 MB

    k_fwd_iter<<<dim3(64 * CD / 2), dim3(512), 0, stream>>>(x, log_alpha, raw_tau,
                                                            raw_omega, u_ws);
    k_inv<<<dim3(64 * KM), dim3(1024), 0, stream>>>(u_ws, out);
}

// Round 11
// 352.257 us; speedup vs baseline: 1.1450x; 1.1183x over previous
//
#include <hip/hip_runtime.h>
#include <math.h>

#ifndef M_PI
#define M_PI 3.14159265358979323846
#endif

#define T_LEN 4096
#define M_LEN 2048   // T/2, complex FFT length
#define NFREQ 2049   // T/2 + 1
#define KM 8         // modes
#define LI 8         // iterations
#define CD 16        // channels

// LDS XOR swizzle on float2 index (bijective on [0,2048); SWZ(2048)==2048).
// Spreads the early-stage stride-2/4 Stockham scatter writes across banks
// (validated in r4: SQ_LDS_BANK_CONFLICT 4.19M -> 1.56M). Reads of 16
// consecutive indices stay contiguous within each 16-chunk -> conflict-free.
#define SWZ(i) ((i) ^ (((i) >> 4) & 15))

// Stockham radix-2 DIF, N=2048, ping-pong (proven k_fwd engine, sign=-1 fwd).
template <int NT>
__device__ __forceinline__ float2* fft2048(float2* a, float2* b, int tid, float sign) {
    float2* src = a;
    float2* dst = b;
    int l = 1024;
    #pragma unroll 1
    for (int s = 0; s < 11; ++s) {
        float piol = sign * (float)M_PI / (float)l;
        #pragma unroll
        for (int ii = 0; ii < 1024 / NT; ++ii) {
            int i = tid + ii * NT;
            int j = i >> s;
            float2 A = src[i];
            float2 B = src[i + 1024];
            float ang = piol * (float)j;
            float sw, cw;
            __sincosf(ang, &sw, &cw);
            float2 sum = make_float2(A.x + B.x, A.y + B.y);
            float2 dif = make_float2(A.x - B.x, A.y - B.y);
            float2 tw = make_float2(dif.x * cw - dif.y * sw, dif.x * sw + dif.y * cw);
            int p = i + (j << s);
            dst[p] = sum;
            dst[p + (1 << s)] = tw;
        }
        __syncthreads();
        float2* t = src; src = dst; dst = t;
        l >>= 1;
    }
    return src;
}

// K1: r2's proven shell (512 threads, 1 row per block, radix-2 FFT) with the
// r9-validated reduced Jacobi (carried SUM(u), h=lambda/2 with pre-halved tau,
// layer-0 special case). The r9 radix-8/2-row variant was ~10us slower
// (32-float FFT live set at an 8-wave/EU 64-reg target) — reverted.
__global__ void __launch_bounds__(512)
k_fwd_iter(const float* __restrict__ x,
           const float* __restrict__ log_alpha,
           const float* __restrict__ raw_tau,
           const float* __restrict__ raw_omega,
           float2* __restrict__ u_ws)
{
    __shared__ float2 bufA[M_LEN];
    __shared__ float2 bufB[M_LEN];
    __shared__ float s_2a[LI * KM];
    __shared__ float s_tau2[LI];      // 0.5 * softplus(raw_tau)
    __shared__ float s_om[KM];

    const int tid = threadIdx.x;
    const int row = blockIdx.x;       // b*16 + c
    const int b = row >> 4;
    const int c = row & 15;

    if (tid < LI * KM) s_2a[tid]   = 2.0f * __expf(log_alpha[tid]);
    if (tid < LI)      s_tau2[tid] = 0.5f * log1pf(__expf(raw_tau[tid]));
    if (tid < KM)      s_om[tid]   = 0.5f / (1.0f + __expf(-raw_omega[tid]));

    // pack z[n] = x[2n] + i*x[2n+1]
    const float* xr = x + (size_t)b * T_LEN * CD + c;
    #pragma unroll
    for (int q = 0; q < 4; ++q) {
        int n = tid + q * 512;
        float e = xr[(size_t)(2 * n) * CD];
        float o = xr[(size_t)(2 * n + 1) * CD];
        bufA[n] = make_float2(e, o);
    }
    __syncthreads();

    float2* Z = fft2048<512>(bufA, bufB, tid, -1.0f);   // ends in bufB

    const size_t sb = (size_t)(b * (KM * CD) + c);

    for (int f = tid; f < NFREQ; f += 512) {
        float2 Zk = Z[f & (M_LEN - 1)];
        float2 Zm = Z[(M_LEN - f) & (M_LEN - 1)];
        float2 E = make_float2(0.5f * (Zk.x + Zm.x), 0.5f * (Zk.y - Zm.y));
        float2 D = make_float2(0.5f * (Zk.x - Zm.x), 0.5f * (Zk.y + Zm.y));
        float2 O = make_float2(D.y, -D.x);
        float ang = -2.0f * (float)M_PI * (float)f / (float)T_LEN;
        float sw, cw;
        __sincosf(ang, &sw, &cw);
        float fhx = E.x + cw * O.x - sw * O.y;
        float fhy = E.y + cw * O.y + sw * O.x;

        float freq = (float)f * (0.5f / (float)M_LEN);
        float dd[KM];
        #pragma unroll
        for (int k = 0; k < KM; ++k) {
            float d = freq - s_om[k];
            dd[k] = d * d;
        }

        float2 u[KM];
        float sx, sy;                 // carried SUM(u)
        float hx, hy;                 // 0.5 * lambda

        // layer 0: u=0, lambda=0 -> b = fh, u[k] = b * r[k]
        {
            float nsx = 0.f, nsy = 0.f;
            #pragma unroll
            for (int k = 0; k < KM; ++k) {
                float den = fmaf(s_2a[k], dd[k], 1.0f);
                float r = __builtin_amdgcn_rcpf(den);
                float ux = fhx * r;
                float uy = fhy * r;
                u[k].x = ux; u[k].y = uy;
                nsx += ux; nsy += uy;
            }
            hx = s_tau2[0] * (fhx - nsx);
            hy = s_tau2[0] * (fhy - nsy);
            sx = nsx; sy = nsy;
        }

        // layers 1..7
        #pragma unroll
        for (int l = 1; l < LI; ++l) {
            float bx = fhx - sx + hx;
            float by = fhy - sy + hy;
            float nsx = 0.f, nsy = 0.f;
            #pragma unroll
            for (int k = 0; k < KM; ++k) {
                float den = fmaf(s_2a[l * KM + k], dd[k], 1.0f);
                float r = __builtin_amdgcn_rcpf(den);
                float ux = (bx + u[k].x) * r;
                float uy = (by + u[k].y) * r;
                u[k].x = ux; u[k].y = uy;
                nsx += ux; nsy += uy;
            }
            hx += s_tau2[l] * (fhx - nsx);
            hy += s_tau2[l] * (fhy - nsy);
            sx = nsx; sy = nsy;
        }

        #pragma unroll
        for (int k = 0; k < KM; ++k) {
            u_ws[(sb + (size_t)k * CD) * NFREQ + f] = u[k];
        }
    }
}

// ---- one radix-2 Stockham stage with a PRE-HOISTED twiddle (inverse sign) ----
#define R2STAGE(S, SRC, DST, CW, SN) {                                        \
    int j_ = tid >> (S);                                                      \
    float2 A_ = SRC[SWZ(tid)];                                                \
    float2 B_ = SRC[SWZ(tid + 1024)];                                         \
    float2 sum_ = make_float2(A_.x + B_.x, A_.y + B_.y);                      \
    float2 dif_ = make_float2(A_.x - B_.x, A_.y - B_.y);                      \
    float2 tw_ = make_float2(dif_.x * (CW) - dif_.y * (SN),                   \
                             dif_.x * (SN) + dif_.y * (CW));                  \
    int p_ = tid + (j_ << (S));                                               \
    DST[SWZ(p_)] = sum_;                                                      \
    DST[SWZ(p_ + (1 << (S)))] = tw_;                                          \
    __syncthreads();                                                          \
}

// stage 9: j = tid>>9 in {0,1}; inverse twiddle = 1 or +i (tw = i*dif)
#define R2STAGE9(SRC, DST) {                                                  \
    float2 A_ = SRC[SWZ(tid)];                                                \
    float2 B_ = SRC[SWZ(tid + 1024)];                                         \
    float2 sum_ = make_float2(A_.x + B_.x, A_.y + B_.y);                      \
    float2 dif_ = make_float2(A_.x - B_.x, A_.y - B_.y);                      \
    float2 tw_ = (tid & 512) ? make_float2(-dif_.y, dif_.x) : dif_;           \
    int p_ = tid + ((tid >> 9) << 9);                                         \
    DST[SWZ(p_)] = sum_;                                                      \
    DST[SWZ(p_ + 512)] = tw_;                                                 \
    __syncthreads();                                                          \
}

// stage 10: j = 0 always; twiddle = 1
#define R2STAGE10(SRC, DST) {                                                 \
    float2 A_ = SRC[SWZ(tid)];                                                \
    float2 B_ = SRC[SWZ(tid + 1024)];                                         \
    DST[SWZ(tid)] = make_float2(A_.x + B_.x, A_.y + B_.y);                    \
    DST[SWZ(tid + 1024)] = make_float2(A_.x - B_.x, A_.y - B_.y);             \
    __syncthreads();                                                          \
}

// K2: r0's proven allocator-safe shape (16 sequential channels, AGPR-resident
// val[], contiguous 256B store) with two deltas:
//  1. CHANNEL-INVARIANT TWIDDLE HOIST: thread tid does the identical butterfly
//     position in all 16 FFTs; stage-s twiddle = exp(i*pi*(tid&~(2^s-1))/1024)
//     and repack twiddle = exp(i*pi*tid/2048) (2nd angle = 1st + pi/2, derived
//     by swap/negate). 9 sincos + 1 ONCE instead of ~200 per thread. Stages
//     fully unrolled with NAMED twiddles (a rolled loop would runtime-index
//     them -> alloca -> scratch, the r4-r8 failure mode).
//  2. SWZ on the LDS buffers (kills the early-stage scatter-write conflicts).
__global__ void __launch_bounds__(1024)
k_inv(const float2* __restrict__ u_ws, float* __restrict__ out)
{
    __shared__ float2 bufA[NFREQ];
    __shared__ float2 bufB[M_LEN];
    const int tid = threadIdx.x;
    const int bk = blockIdx.x;        // b*8 + k

    // ---- hoisted channel-invariant twiddles ----
    float cs0,sn0,cs1,sn1,cs2,sn2,cs3,sn3,cs4,sn4,cs5,sn5,cs6,sn6,cs7,sn7,cs8,sn8;
    {
        const float w = (float)M_PI / 1024.0f;
        __sincosf(w * (float)tid,          &sn0, &cs0);
        __sincosf(w * (float)(tid & ~1),   &sn1, &cs1);
        __sincosf(w * (float)(tid & ~3),   &sn2, &cs2);
        __sincosf(w * (float)(tid & ~7),   &sn3, &cs3);
        __sincosf(w * (float)(tid & ~15),  &sn4, &cs4);
        __sincosf(w * (float)(tid & ~31),  &sn5, &cs5);
        __sincosf(w * (float)(tid & ~63),  &sn6, &cs6);
        __sincosf(w * (float)(tid & ~127), &sn7, &cs7);
        __sincosf(w * (float)(tid & ~255), &sn8, &cs8);
    }
    float csR, snR;                   // repack: ang = pi*tid/2048
    __sincosf(((float)M_PI / 2048.0f) * (float)tid, &snR, &csR);

    float val[CD][4];                 // [c][t offset] — r0-proven AGPR residency

    #pragma unroll
    for (int c = 0; c < CD; ++c) {
        const float2* sp = u_ws + (size_t)(bk * CD + c) * NFREQ;
        bufA[SWZ(tid)] = sp[tid];
        bufA[SWZ(tid + 1024)] = sp[tid + 1024];
        if (tid == 0) bufA[2048] = sp[2048];   // SWZ(2048)==2048
        __syncthreads();

        // irfft repack: Z[j] = (E[j] + i*O[j]) / M  -> bufB
        const float sc = 1.0f / (float)M_LEN;
        #pragma unroll
        for (int jj = 0; jj < 2; ++jj) {
            int j = tid + jj * 1024;
            // jj=0: (cw,sw) = (csR,snR); jj=1: ang += pi/2 -> (-snR, csR)
            float cw = jj ? -snR : csR;
            float sw = jj ?  csR : snR;
            float2 Xj = bufA[SWZ(j)];
            float2 Xm = (j > 0) ? bufA[SWZ(M_LEN - j)] : bufA[2048];
            float2 E = make_float2(0.5f * (Xj.x + Xm.x), 0.5f * (Xj.y - Xm.y));
            float2 D = make_float2(0.5f * (Xj.x - Xm.x), 0.5f * (Xj.y + Xm.y));
            float2 O = make_float2(cw * D.x - sw * D.y, cw * D.y + sw * D.x);
            bufB[SWZ(j)] = make_float2((E.x - O.y) * sc, (E.y + O.x) * sc);
        }
        __syncthreads();

        // 11 unrolled stages, ping-pong B->A->B->...->A (result in bufA)
        R2STAGE(0, bufB, bufA, cs0, sn0);
        R2STAGE(1, bufA, bufB, cs1, sn1);
        R2STAGE(2, bufB, bufA, cs2, sn2);
        R2STAGE(3, bufA, bufB, cs3, sn3);
        R2STAGE(4, bufB, bufA, cs4, sn4);
        R2STAGE(5, bufA, bufB, cs5, sn5);
        R2STAGE(6, bufB, bufA, cs6, sn6);
        R2STAGE(7, bufA, bufB, cs7, sn7);
        R2STAGE(8, bufB, bufA, cs8, sn8);
        R2STAGE9(bufA, bufB);
        R2STAGE10(bufB, bufA);

        float2 z0 = bufA[SWZ(2 * tid)];
        float2 z1 = bufA[SWZ(2 * tid + 1)];
        val[c][0] = z0.x;   // t = 4*tid + 0 (even -> Re)
        val[c][1] = z0.y;   // t = 4*tid + 1 (odd  -> Im)
        val[c][2] = z1.x;
        val[c][3] = z1.y;
        __syncthreads();    // before next c overwrites buffers
    }

    // Each thread owns out[b, k, 4*tid .. 4*tid+3, 0..15]: contiguous 256 B.
    float4* op = (float4*)(out + ((size_t)bk * T_LEN + (size_t)(4 * tid)) * CD);
    #pragma unroll
    for (int r = 0; r < 4; ++r) {
        #pragma unroll
        for (int g = 0; g < 4; ++g) {
            op[r * 4 + g] = make_float4(val[4 * g + 0][r], val[4 * g + 1][r],
                                        val[4 * g + 2][r], val[4 * g + 3][r]);
        }
    }
}

extern "C" void kernel_launch(void* const* d_in, const int* in_sizes, int n_in,
                              void* d_out, int out_size, void* d_ws, size_t ws_size,
                              hipStream_t stream) {
    const float* x         = (const float*)d_in[0];
    const float* log_alpha = (const float*)d_in[1];
    const float* raw_tau   = (const float*)d_in[2];
    const float* raw_omega = (const float*)d_in[3];
    float* out = (float*)d_out;
    float2* u_ws = (float2*)d_ws;   // needs 8192 * 2049 * 8 B = 134.3 MB

    k_fwd_iter<<<dim3(64 * CD), dim3(512), 0, stream>>>(x, log_alpha, raw_tau,
                                                        raw_omega, u_ws);
    k_inv<<<dim3(64 * KM), dim3(1024), 0, stream>>>(u_ws, out);
}